// Round 5
// baseline (921.138 us; speedup 1.0000x reference)
//
#include <hip/hip_runtime.h>
#include <hip/hip_bf16.h>
#include <math.h>

// GAT 2-layer inference on MI355X.
// R1: gemm1 lane=row + LDS tile (broadcast-load fix).
// R2: bucketed CSR build (write-amp fix); fused single-sweep agg; gemm2 thread=row.
// R3: gemm1 -> MFMA bf16; h1/h2 gather tables bf16.
// R4: agg1/agg2 two-phase (lane-parallel weights + shfl-broadcast fma) --
//     was 77 cyc/edge of redundant per-lane exp + addr math (VALUBusy 78%).
//     h2b rows padded to 48 ushorts (96B, aligned -> 2 lines/gather).

#define DEV __device__ __forceinline__

constexpr int N_NODES = 100000;
constexpr int N_EDGES = 3200000;
constexpr int F_IN    = 500;
constexpr int HEADS   = 8;
constexpr int HID     = 8;
constexpr int D1      = HEADS * HID;   // 64
constexpr int NC      = 41;
constexpr int H2S     = 48;            // padded h2b row stride (ushorts)

// bucketed CSR build
constexpr int NB    = 196;     // buckets of 512 nodes (dst >> 9)
constexpr int BCAP  = 20480;   // staging capacity per bucket (avg 16327)
constexpr int SEPT  = 16;      // edges per thread in bucket_scatter
constexpr int SCHUNK = 256 * SEPT;   // 4096 edges per block

// gemm1 MFMA tile
constexpr int LROW  = 520;     // LDS row stride in bf16 (2-way bank alias only)

typedef __attribute__((ext_vector_type(8))) short bf16x8;
typedef __attribute__((ext_vector_type(4))) float f32x4;

DEV float bf2f(unsigned short u) {
    return __uint_as_float(((unsigned int)u) << 16);
}
DEV unsigned short f2b(float f) {   // RNE f32 -> bf16 bits
    unsigned int u = __float_as_uint(f);
    unsigned int r = (u + 0x7FFFu + ((u >> 16) & 1u)) >> 16;
    return (unsigned short)r;
}
DEV float leaky(float e) { return e > 0.f ? e : 0.2f * e; }

// ---------------------------------------------------------------- detect + convert weights
__global__ void k_detect_convert(const void* xraw, const void* eraw,
                                 const void* w1, const void* a1s, const void* a1d,
                                 const void* w2, const void* a2s, const void* a2d,
                                 unsigned short* W1frag, float* A1Sf, float* A1Df,
                                 float* W2f, float* A2Sf, float* A2Df,
                                 int* flags) {
    __shared__ int sf;
    if (threadIdx.x == 0) {
        const unsigned short* xu = (const unsigned short*)xraw;
        int valid = 0;
        for (int i = 0; i < 64; i++) {
            unsigned short v = xu[2 * i];
            int e = (v >> 7) & 0xFF;
            if (e == 0 || (e >= 90 && e <= 150)) valid++;
        }
        int xf32 = (valid < 56) ? 1 : 0;
        const unsigned int* eu = (const unsigned int*)eraw;
        int zeros = 0;
        for (int k = 0; k < 64; k++)
            if (eu[2 * k + 1] == 0u) zeros++;
        int e64 = (zeros == 64) ? 1 : 0;
        flags[0] = xf32;
        flags[1] = e64;
        sf = xf32;
    }
    __syncthreads();
    bool f32 = (sf != 0);
    auto conv = [&](const void* src, float* dst, int n) {
        if (f32) {
            const float* s = (const float*)src;
            for (int i = threadIdx.x; i < n; i += blockDim.x) dst[i] = s[i];
        } else {
            const unsigned short* s = (const unsigned short*)src;
            for (int i = threadIdx.x; i < n; i += blockDim.x) dst[i] = bf2f(s[i]);
        }
    };
    conv(a1s, A1Sf, HEADS * HID);
    conv(a1d, A1Df, HEADS * HID);
    conv(w2, W2f, D1 * NC);
    conv(a2s, A2Sf, NC);
    conv(a2d, A2Df, NC);
    // W1frag: per-wave MFMA B-fragment order
    for (int idx = threadIdx.x; idx < 4 * 16 * 64 * 8; idx += blockDim.x) {
        int wid = idx >> 13, kb = (idx >> 9) & 15, ln = (idx >> 3) & 63, j = idx & 7;
        int k = kb * 32 + (ln >> 4) * 8 + j;
        int n = wid * 16 + (ln & 15);
        unsigned short bits = 0;
        if (k < F_IN) {
            if (f32) bits = f2b(((const float*)w1)[k * D1 + n]);
            else     bits = ((const unsigned short*)w1)[k * D1 + n];
        }
        W1frag[idx] = bits;
    }
}

// ---------------------------------------------------------------- CSR build, pass 1
__global__ __launch_bounds__(256) void k_bucket_scatter(const void* eraw, const int* flags,
                                                        int* bucket_cnt, unsigned int* staging) {
    __shared__ int bh[NB];
    const int t = threadIdx.x;
    for (int i = t; i < NB; i += 256) bh[i] = 0;
    __syncthreads();
    const bool e64 = flags[1] != 0;
    const unsigned int* eu = (const unsigned int*)eraw;
    const int e0 = blockIdx.x * SCHUNK;
    int sv[SEPT], dv[SEPT];
#pragma unroll
    for (int k = 0; k < SEPT; k++) {
        int i = e0 + k * 256 + t;
        if (i < N_EDGES) {
            if (e64) { sv[k] = (int)eu[2 * i]; dv[k] = (int)eu[2 * (N_EDGES + i)]; }
            else     { sv[k] = (int)eu[i];     dv[k] = (int)eu[N_EDGES + i]; }
            atomicAdd(&bh[dv[k] >> 9], 1);
        } else dv[k] = -1;
    }
    __syncthreads();
    for (int i = t; i < NB; i += 256) {
        int c = bh[i];
        int base = c ? atomicAdd(&bucket_cnt[i], c) : 0;
        bh[i] = i * BCAP + base;
    }
    __syncthreads();
#pragma unroll
    for (int k = 0; k < SEPT; k++) {
        if (dv[k] >= 0) {
            int b = dv[k] >> 9;
            int slot = atomicAdd(&bh[b], 1);
            staging[slot] = (unsigned)sv[k] | ((unsigned)(dv[k] & 511) << 17);
        }
    }
}

// pass 2: scan bucket counts -> CSR bucket bases
__global__ void k_cscan(const int* bucket_cnt, int* cbase, int* off) {
    __shared__ int s[256];
    int t = threadIdx.x;
    s[t] = (t < NB) ? bucket_cnt[t] : 0;
    __syncthreads();
    for (int o = 1; o < 256; o <<= 1) {
        int v = (t >= o) ? s[t - o] : 0;
        __syncthreads();
        s[t] += v;
        __syncthreads();
    }
    if (t < NB) cbase[t + 1] = s[t];
    if (t == 0) { cbase[0] = 0; off[N_NODES] = N_EDGES; }
}

// pass 3: per-bucket LDS counters; csr writes confined to ~65KB region
__global__ __launch_bounds__(512) void k_csr_build(const unsigned int* __restrict__ staging,
                                                   const int* __restrict__ bucket_cnt,
                                                   const int* __restrict__ cbase,
                                                   int* __restrict__ off, int* __restrict__ csr) {
    __shared__ int sdeg[512];
    __shared__ int scur[512];
    const int t = threadIdx.x;
    const int b = blockIdx.x;
    const int n0 = b << 9;
    const int start = b * BCAP;
    const int end = start + bucket_cnt[b];
    const int base = cbase[b];
    sdeg[t] = 0;
    __syncthreads();
    for (int i = start + t; i < end; i += 512)
        atomicAdd(&sdeg[staging[i] >> 17], 1);
    __syncthreads();
    int d = sdeg[t];
    for (int o = 1; o < 512; o <<= 1) {
        int v = (t >= o) ? sdeg[t - o] : 0;
        __syncthreads();
        sdeg[t] += v;
        __syncthreads();
    }
    int excl = sdeg[t] - d;
    if (n0 + t < N_NODES) off[n0 + t] = base + excl;
    scur[t] = base + excl;
    __syncthreads();
    for (int i = start + t; i < end; i += 512) {
        unsigned v = staging[i];
        int slot = atomicAdd(&scur[v >> 17], 1);
        csr[slot] = (int)(v & 0x1FFFFu);
    }
}

// ---------------------------------------------------------------- GEMM1: MFMA bf16
__global__ __launch_bounds__(256) void k_gemm1(const void* xraw, const int* flags,
                                               const unsigned short* __restrict__ W1frag,
                                               const float* A1Sf, const float* A1Df,
                                               unsigned short* __restrict__ h1b,
                                               float* __restrict__ as1,
                                               float* __restrict__ ad1) {
    __shared__ unsigned short ldsx[64 * LROW];
    const int t = threadIdx.x;
    const int r0 = blockIdx.x * 64;
    const bool xf32 = flags[0] != 0;
#pragma unroll
    for (int it = 0; it < 32; it++) {
        int s = it * 256 + t;
        int row = s >> 7, c4 = s & 127;
        int row_g = r0 + row;
        ushort4 v = make_ushort4(0, 0, 0, 0);
        if (c4 < 125 && row_g < N_NODES) {
            if (xf32) {
                float4 f = *(const float4*)((const float*)xraw + (size_t)row_g * F_IN + c4 * 4);
                v = make_ushort4(f2b(f.x), f2b(f.y), f2b(f.z), f2b(f.w));
            } else {
                v = *(const ushort4*)((const unsigned short*)xraw + (size_t)row_g * F_IN + c4 * 4);
            }
        }
        *(ushort4*)(ldsx + row * LROW + c4 * 4) = v;
    }
    __syncthreads();

    const int lane = t & 63;
    const int wid = __builtin_amdgcn_readfirstlane(t >> 6);
    const int m = lane & 15, q = lane >> 4;
    f32x4 acc[4] = {{0.f, 0.f, 0.f, 0.f}, {0.f, 0.f, 0.f, 0.f},
                    {0.f, 0.f, 0.f, 0.f}, {0.f, 0.f, 0.f, 0.f}};
    const unsigned short* wf = W1frag + (size_t)wid * 8192;
#pragma unroll 4
    for (int kb = 0; kb < 16; kb++) {
        bf16x8 b = *(const bf16x8*)(wf + (kb * 64 + lane) * 8);
#pragma unroll
        for (int mb = 0; mb < 4; mb++) {
            bf16x8 a = *(const bf16x8*)(ldsx + (mb * 16 + m) * LROW + kb * 32 + q * 8);
            acc[mb] = __builtin_amdgcn_mfma_f32_16x16x32_bf16(a, b, acc[mb], 0, 0, 0);
        }
    }
    const int col = wid * 16 + m;
    const float a_s = A1Sf[col], a_d = A1Df[col];
    const int h = 2 * wid + (m >> 3);
#pragma unroll
    for (int mb = 0; mb < 4; mb++) {
#pragma unroll
        for (int reg = 0; reg < 4; reg++) {
            int gr = r0 + mb * 16 + q * 4 + reg;
            float vacc = acc[mb][reg];
            bool ok = gr < N_NODES;
            if (ok) h1b[(size_t)gr * D1 + col] = f2b(vacc);
            float ts = vacc * a_s, td = vacc * a_d;
            ts += __shfl_xor(ts, 1, 64); td += __shfl_xor(td, 1, 64);
            ts += __shfl_xor(ts, 2, 64); td += __shfl_xor(td, 2, 64);
            ts += __shfl_xor(ts, 4, 64); td += __shfl_xor(td, 4, 64);
            if (ok && (lane & 7) == 0) {
                as1[gr * HEADS + h] = ts;
                ad1[gr * HEADS + h] = td;
            }
        }
    }
}

// ---------------------------------------------------------------- layer-1 aggregation + ELU
// Two-phase per 8-edge chunk: phase A lane=(edge el, head h) computes weight
// (one exp per edge-head total); phase B shfl-broadcasts (w, src) and does
// only load+fma per edge per lane.
__global__ __launch_bounds__(256) void k_agg1(const int* __restrict__ csr,
                                              const int* __restrict__ off,
                                              const unsigned short* __restrict__ h1b,
                                              const float* __restrict__ as1,
                                              const float* __restrict__ ad1,
                                              float* __restrict__ h1e) {
    const int lane = threadIdx.x & 63;
    const int n = (blockIdx.x * blockDim.x + threadIdx.x) >> 6;
    if (n >= N_NODES) return;
    const int beg = off[n], end = off[n + 1];
    const int el = lane >> 3, h = lane & 7;
    const int h0 = el;                 // head owning this lane's output column
    const float adh = ad1[n * HEADS + h];
    float acc = 0.f, dsum = 0.f;
    for (int base = beg; base < end; base += 8) {
        int i = base + el;
        bool v = i < end;
        int s = csr[v ? i : beg];
        float a = as1[s * HEADS + h];
        float wv = v ? __expf(leaky(a + adh)) : 0.f;
        dsum += wv;
        int cnt = end - base; if (cnt > 8) cnt = 8;
        for (int e = 0; e < cnt; e++) {
            int idx = e * 8 + h0;
            float we = __shfl(wv, idx, 64);
            int se = __shfl(s, idx, 64);
            float g = bf2f(h1b[se * D1 + lane]);
            acc = fmaf(we, g, acc);
        }
    }
    // dsum reduction over edge-groups (bits 3..5) -> per-lane total for head h
    dsum += __shfl_xor(dsum, 8, 64);
    dsum += __shfl_xor(dsum, 16, 64);
    dsum += __shfl_xor(dsum, 32, 64);
    float rd = 1.f / (dsum + 1e-16f);
    float rdn = __shfl(rd, h0, 64);    // lane h0 holds head h0's total
    float val = acc * rdn;
    float o = val > 0.f ? val : (__expf(val) - 1.f);   // ELU
    h1e[(size_t)n * D1 + lane] = o;
}

// ---------------------------------------------------------------- GEMM2 (thread=row)
__global__ __launch_bounds__(256) void k_gemm2(const float* __restrict__ h1e,
                                               const float* __restrict__ W2f,
                                               const float* __restrict__ A2Sf,
                                               const float* __restrict__ A2Df,
                                               unsigned short* __restrict__ h2b,
                                               float* __restrict__ as2,
                                               float* __restrict__ ad2) {
    const int row = blockIdx.x * blockDim.x + threadIdx.x;
    if (row >= N_NODES) return;
    float acc[NC];
#pragma unroll
    for (int c = 0; c < NC; c++) acc[c] = 0.f;
    const float* xr = h1e + (size_t)row * D1;
    for (int k = 0; k < D1; k += 4) {
        float4 hv = *(const float4*)(xr + k);
#pragma unroll
        for (int c = 0; c < NC; c++) {
            acc[c] = fmaf(hv.x, W2f[(k + 0) * NC + c], acc[c]);
            acc[c] = fmaf(hv.y, W2f[(k + 1) * NC + c], acc[c]);
            acc[c] = fmaf(hv.z, W2f[(k + 2) * NC + c], acc[c]);
            acc[c] = fmaf(hv.w, W2f[(k + 3) * NC + c], acc[c]);
        }
    }
    float ts = 0.f, td = 0.f;
#pragma unroll
    for (int c = 0; c < NC; c++) {
        h2b[(size_t)row * H2S + c] = f2b(acc[c]);
        ts = fmaf(acc[c], A2Sf[c], ts);
        td = fmaf(acc[c], A2Df[c], td);
    }
    as2[row] = ts;
    ad2[row] = td;
}

// ---------------------------------------------------------------- layer-2 aggregation + log_softmax
// Two-phase per 64-edge chunk: phase A lane=edge computes weight (one exp per
// edge total); phase B readlane-broadcasts (w, row-offset), load+fma per edge.
__global__ __launch_bounds__(256) void k_agg2(const int* __restrict__ csr,
                                              const int* __restrict__ off,
                                              const unsigned short* __restrict__ h2b,
                                              const float* __restrict__ as2,
                                              const float* __restrict__ ad2,
                                              const int* flags, void* out) {
    const int lane = threadIdx.x & 63;
    const int n = (blockIdx.x * blockDim.x + threadIdx.x) >> 6;
    if (n >= N_NODES) return;
    const int beg = off[n], end = off[n + 1];
    const float ad = ad2[n];
    const bool act = lane < NC;
    const int cl = act ? lane : 0;
    float acc = 0.f, dsum = 0.f;
    for (int base = beg; base < end; base += 64) {
        int i = base + lane;
        bool v = i < end;
        int s = csr[v ? i : beg];
        float a = as2[s];
        float wv = v ? __expf(leaky(a + ad)) : 0.f;
        dsum += wv;
        int ro = s * H2S;
        int cnt = end - base; if (cnt > 64) cnt = 64;
        for (int e = 0; e < cnt; e++) {
            float we = __shfl(wv, e, 64);
            int re = __shfl(ro, e, 64);
            float g = bf2f(h2b[re + cl]);
            acc = fmaf(we, g, acc);
        }
    }
#pragma unroll
    for (int o = 1; o < 64; o <<= 1) dsum += __shfl_xor(dsum, o, 64);
    float val = acc / (dsum + 1e-16f);
    // log_softmax over the 41 classes
    float v = act ? val : -INFINITY;
    float m = v;
#pragma unroll
    for (int o = 1; o < 64; o <<= 1) m = fmaxf(m, __shfl_xor(m, o, 64));
    float ex = act ? __expf(val - m) : 0.f;
#pragma unroll
    for (int o = 1; o < 64; o <<= 1) ex += __shfl_xor(ex, o, 64);
    float res = val - m - __logf(ex);
    if (act) {
        if (flags[0])
            ((float*)out)[(size_t)n * NC + lane] = res;
        else
            ((__hip_bfloat16*)out)[(size_t)n * NC + lane] = __float2bfloat16(res);
    }
}

// ---------------------------------------------------------------- host
extern "C" void kernel_launch(void* const* d_in, const int* in_sizes, int n_in,
                              void* d_out, int out_size, void* d_ws, size_t ws_size,
                              hipStream_t stream) {
    char* p = (char*)d_ws;
    auto alloc = [&](size_t bytes) -> void* {
        void* r = (void*)p;
        p += (bytes + 255) & ~(size_t)255;
        return r;
    };
    int* flags  = (int*)alloc(16);
    unsigned short* W1frag = (unsigned short*)alloc(4 * 16 * 64 * 8 * 2);
    float* A1Sf = (float*)alloc(HEADS * HID * 4);
    float* A1Df = (float*)alloc(HEADS * HID * 4);
    float* W2f  = (float*)alloc((size_t)D1 * NC * 4);
    float* A2Sf = (float*)alloc(NC * 4);
    float* A2Df = (float*)alloc(NC * 4);
    unsigned short* h1b = (unsigned short*)alloc((size_t)N_NODES * D1 * 2);
    float* as1  = (float*)alloc((size_t)N_NODES * HEADS * 4);
    float* ad1  = (float*)alloc((size_t)N_NODES * HEADS * 4);
    float* h1e  = (float*)alloc((size_t)N_NODES * D1 * 4);
    unsigned short* h2b = (unsigned short*)alloc((size_t)N_NODES * H2S * 2);
    float* as2  = (float*)alloc((size_t)N_NODES * 4);
    float* ad2  = (float*)alloc((size_t)N_NODES * 4);
    int* off    = (int*)alloc((size_t)(N_NODES + 1) * 4);
    int* csr    = (int*)alloc((size_t)N_EDGES * 4);
    int* bucket_cnt = (int*)alloc((size_t)NB * 4);
    int* cbase      = (int*)alloc((size_t)(NB + 1) * 4);
    // staging aliases h1e (dead until agg1 writes h1e): 16.06 MB <= 25.6 MB
    unsigned int* staging = (unsigned int*)h1e;

    hipMemsetAsync(bucket_cnt, 0, (size_t)NB * 4, stream);

    k_detect_convert<<<1, 256, 0, stream>>>(d_in[0], d_in[1], d_in[2], d_in[3],
                                            d_in[4], d_in[5], d_in[6], d_in[7],
                                            W1frag, A1Sf, A1Df, W2f, A2Sf, A2Df, flags);
    k_bucket_scatter<<<(N_EDGES + SCHUNK - 1) / SCHUNK, 256, 0, stream>>>(d_in[1], flags, bucket_cnt, staging);
    k_cscan<<<1, 256, 0, stream>>>(bucket_cnt, cbase, off);
    k_csr_build<<<NB, 512, 0, stream>>>(staging, bucket_cnt, cbase, off, csr);

    k_gemm1<<<1563, 256, 0, stream>>>(d_in[0], flags, W1frag, A1Sf, A1Df, h1b, as1, ad1);
    k_agg1<<<25000, 256, 0, stream>>>(csr, off, h1b, as1, ad1, h1e);
    k_gemm2<<<391, 256, 0, stream>>>(h1e, W2f, A2Sf, A2Df, h2b, as2, ad2);
    k_agg2<<<25000, 256, 0, stream>>>(csr, off, h2b, as2, ad2, flags, d_out);
}

// Round 6
// 765.183 us; speedup vs baseline: 1.2038x; 1.2038x over previous
//
#include <hip/hip_runtime.h>
#include <hip/hip_bf16.h>
#include <math.h>

// GAT 2-layer inference on MI355X.
// R1: gemm1 lane=row + LDS tile (broadcast-load fix).
// R2: bucketed CSR build (write-amp fix); fused single-sweep agg; gemm2 thread=row.
// R3: gemm1 -> MFMA bf16; h1/h2 gather tables bf16.
// R4 (REGRESSED, reverted in R5): shfl-broadcast two-phase agg -- ds_bpermute
//     latency chains beat the VALU savings. Kept: h2b 96B padded rows.
// R5: aggs back to R3 per-lane form, 8x unroll + 4 independent accumulators.

#define DEV __device__ __forceinline__

constexpr int N_NODES = 100000;
constexpr int N_EDGES = 3200000;
constexpr int F_IN    = 500;
constexpr int HEADS   = 8;
constexpr int HID     = 8;
constexpr int D1      = HEADS * HID;   // 64
constexpr int NC      = 41;
constexpr int H2S     = 48;            // padded h2b row stride (ushorts, 96B aligned)

// bucketed CSR build
constexpr int NB    = 196;     // buckets of 512 nodes (dst >> 9)
constexpr int BCAP  = 20480;   // staging capacity per bucket (avg 16327)
constexpr int SEPT  = 16;      // edges per thread in bucket_scatter
constexpr int SCHUNK = 256 * SEPT;   // 4096 edges per block

// gemm1 MFMA tile
constexpr int LROW  = 520;     // LDS row stride in bf16 (2-way bank alias only)

typedef __attribute__((ext_vector_type(8))) short bf16x8;
typedef __attribute__((ext_vector_type(4))) float f32x4;

DEV float bf2f(unsigned short u) {
    return __uint_as_float(((unsigned int)u) << 16);
}
DEV unsigned short f2b(float f) {   // RNE f32 -> bf16 bits
    unsigned int u = __float_as_uint(f);
    unsigned int r = (u + 0x7FFFu + ((u >> 16) & 1u)) >> 16;
    return (unsigned short)r;
}
DEV float leaky(float e) { return e > 0.f ? e : 0.2f * e; }

// ---------------------------------------------------------------- detect + convert weights
__global__ void k_detect_convert(const void* xraw, const void* eraw,
                                 const void* w1, const void* a1s, const void* a1d,
                                 const void* w2, const void* a2s, const void* a2d,
                                 unsigned short* W1frag, float* A1Sf, float* A1Df,
                                 float* W2f, float* A2Sf, float* A2Df,
                                 int* flags) {
    __shared__ int sf;
    if (threadIdx.x == 0) {
        const unsigned short* xu = (const unsigned short*)xraw;
        int valid = 0;
        for (int i = 0; i < 64; i++) {
            unsigned short v = xu[2 * i];
            int e = (v >> 7) & 0xFF;
            if (e == 0 || (e >= 90 && e <= 150)) valid++;
        }
        int xf32 = (valid < 56) ? 1 : 0;
        const unsigned int* eu = (const unsigned int*)eraw;
        int zeros = 0;
        for (int k = 0; k < 64; k++)
            if (eu[2 * k + 1] == 0u) zeros++;
        int e64 = (zeros == 64) ? 1 : 0;
        flags[0] = xf32;
        flags[1] = e64;
        sf = xf32;
    }
    __syncthreads();
    bool f32 = (sf != 0);
    auto conv = [&](const void* src, float* dst, int n) {
        if (f32) {
            const float* s = (const float*)src;
            for (int i = threadIdx.x; i < n; i += blockDim.x) dst[i] = s[i];
        } else {
            const unsigned short* s = (const unsigned short*)src;
            for (int i = threadIdx.x; i < n; i += blockDim.x) dst[i] = bf2f(s[i]);
        }
    };
    conv(a1s, A1Sf, HEADS * HID);
    conv(a1d, A1Df, HEADS * HID);
    conv(w2, W2f, D1 * NC);
    conv(a2s, A2Sf, NC);
    conv(a2d, A2Df, NC);
    // W1frag: per-wave MFMA B-fragment order
    for (int idx = threadIdx.x; idx < 4 * 16 * 64 * 8; idx += blockDim.x) {
        int wid = idx >> 13, kb = (idx >> 9) & 15, ln = (idx >> 3) & 63, j = idx & 7;
        int k = kb * 32 + (ln >> 4) * 8 + j;
        int n = wid * 16 + (ln & 15);
        unsigned short bits = 0;
        if (k < F_IN) {
            if (f32) bits = f2b(((const float*)w1)[k * D1 + n]);
            else     bits = ((const unsigned short*)w1)[k * D1 + n];
        }
        W1frag[idx] = bits;
    }
}

// ---------------------------------------------------------------- CSR build, pass 1
__global__ __launch_bounds__(256) void k_bucket_scatter(const void* eraw, const int* flags,
                                                        int* bucket_cnt, unsigned int* staging) {
    __shared__ int bh[NB];
    const int t = threadIdx.x;
    for (int i = t; i < NB; i += 256) bh[i] = 0;
    __syncthreads();
    const bool e64 = flags[1] != 0;
    const unsigned int* eu = (const unsigned int*)eraw;
    const int e0 = blockIdx.x * SCHUNK;
    int sv[SEPT], dv[SEPT];
#pragma unroll
    for (int k = 0; k < SEPT; k++) {
        int i = e0 + k * 256 + t;
        if (i < N_EDGES) {
            if (e64) { sv[k] = (int)eu[2 * i]; dv[k] = (int)eu[2 * (N_EDGES + i)]; }
            else     { sv[k] = (int)eu[i];     dv[k] = (int)eu[N_EDGES + i]; }
            atomicAdd(&bh[dv[k] >> 9], 1);
        } else dv[k] = -1;
    }
    __syncthreads();
    for (int i = t; i < NB; i += 256) {
        int c = bh[i];
        int base = c ? atomicAdd(&bucket_cnt[i], c) : 0;
        bh[i] = i * BCAP + base;
    }
    __syncthreads();
#pragma unroll
    for (int k = 0; k < SEPT; k++) {
        if (dv[k] >= 0) {
            int b = dv[k] >> 9;
            int slot = atomicAdd(&bh[b], 1);
            staging[slot] = (unsigned)sv[k] | ((unsigned)(dv[k] & 511) << 17);
        }
    }
}

// pass 2: scan bucket counts -> CSR bucket bases
__global__ void k_cscan(const int* bucket_cnt, int* cbase, int* off) {
    __shared__ int s[256];
    int t = threadIdx.x;
    s[t] = (t < NB) ? bucket_cnt[t] : 0;
    __syncthreads();
    for (int o = 1; o < 256; o <<= 1) {
        int v = (t >= o) ? s[t - o] : 0;
        __syncthreads();
        s[t] += v;
        __syncthreads();
    }
    if (t < NB) cbase[t + 1] = s[t];
    if (t == 0) { cbase[0] = 0; off[N_NODES] = N_EDGES; }
}

// pass 3: per-bucket LDS counters; csr writes confined to ~65KB region
__global__ __launch_bounds__(512) void k_csr_build(const unsigned int* __restrict__ staging,
                                                   const int* __restrict__ bucket_cnt,
                                                   const int* __restrict__ cbase,
                                                   int* __restrict__ off, int* __restrict__ csr) {
    __shared__ int sdeg[512];
    __shared__ int scur[512];
    const int t = threadIdx.x;
    const int b = blockIdx.x;
    const int n0 = b << 9;
    const int start = b * BCAP;
    const int end = start + bucket_cnt[b];
    const int base = cbase[b];
    sdeg[t] = 0;
    __syncthreads();
    for (int i = start + t; i < end; i += 512)
        atomicAdd(&sdeg[staging[i] >> 17], 1);
    __syncthreads();
    int d = sdeg[t];
    for (int o = 1; o < 512; o <<= 1) {
        int v = (t >= o) ? sdeg[t - o] : 0;
        __syncthreads();
        sdeg[t] += v;
        __syncthreads();
    }
    int excl = sdeg[t] - d;
    if (n0 + t < N_NODES) off[n0 + t] = base + excl;
    scur[t] = base + excl;
    __syncthreads();
    for (int i = start + t; i < end; i += 512) {
        unsigned v = staging[i];
        int slot = atomicAdd(&scur[v >> 17], 1);
        csr[slot] = (int)(v & 0x1FFFFu);
    }
}

// ---------------------------------------------------------------- GEMM1: MFMA bf16
__global__ __launch_bounds__(256) void k_gemm1(const void* xraw, const int* flags,
                                               const unsigned short* __restrict__ W1frag,
                                               const float* A1Sf, const float* A1Df,
                                               unsigned short* __restrict__ h1b,
                                               float* __restrict__ as1,
                                               float* __restrict__ ad1) {
    __shared__ unsigned short ldsx[64 * LROW];
    const int t = threadIdx.x;
    const int r0 = blockIdx.x * 64;
    const bool xf32 = flags[0] != 0;
#pragma unroll
    for (int it = 0; it < 32; it++) {
        int s = it * 256 + t;
        int row = s >> 7, c4 = s & 127;
        int row_g = r0 + row;
        ushort4 v = make_ushort4(0, 0, 0, 0);
        if (c4 < 125 && row_g < N_NODES) {
            if (xf32) {
                float4 f = *(const float4*)((const float*)xraw + (size_t)row_g * F_IN + c4 * 4);
                v = make_ushort4(f2b(f.x), f2b(f.y), f2b(f.z), f2b(f.w));
            } else {
                v = *(const ushort4*)((const unsigned short*)xraw + (size_t)row_g * F_IN + c4 * 4);
            }
        }
        *(ushort4*)(ldsx + row * LROW + c4 * 4) = v;
    }
    __syncthreads();

    const int lane = t & 63;
    const int wid = __builtin_amdgcn_readfirstlane(t >> 6);
    const int m = lane & 15, q = lane >> 4;
    f32x4 acc[4] = {{0.f, 0.f, 0.f, 0.f}, {0.f, 0.f, 0.f, 0.f},
                    {0.f, 0.f, 0.f, 0.f}, {0.f, 0.f, 0.f, 0.f}};
    const unsigned short* wf = W1frag + (size_t)wid * 8192;
#pragma unroll 4
    for (int kb = 0; kb < 16; kb++) {
        bf16x8 b = *(const bf16x8*)(wf + (kb * 64 + lane) * 8);
#pragma unroll
        for (int mb = 0; mb < 4; mb++) {
            bf16x8 a = *(const bf16x8*)(ldsx + (mb * 16 + m) * LROW + kb * 32 + q * 8);
            acc[mb] = __builtin_amdgcn_mfma_f32_16x16x32_bf16(a, b, acc[mb], 0, 0, 0);
        }
    }
    const int col = wid * 16 + m;
    const float a_s = A1Sf[col], a_d = A1Df[col];
    const int h = 2 * wid + (m >> 3);
#pragma unroll
    for (int mb = 0; mb < 4; mb++) {
#pragma unroll
        for (int reg = 0; reg < 4; reg++) {
            int gr = r0 + mb * 16 + q * 4 + reg;
            float vacc = acc[mb][reg];
            bool ok = gr < N_NODES;
            if (ok) h1b[(size_t)gr * D1 + col] = f2b(vacc);
            float ts = vacc * a_s, td = vacc * a_d;
            ts += __shfl_xor(ts, 1, 64); td += __shfl_xor(td, 1, 64);
            ts += __shfl_xor(ts, 2, 64); td += __shfl_xor(td, 2, 64);
            ts += __shfl_xor(ts, 4, 64); td += __shfl_xor(td, 4, 64);
            if (ok && (lane & 7) == 0) {
                as1[gr * HEADS + h] = ts;
                ad1[gr * HEADS + h] = td;
            }
        }
    }
}

// ---------------------------------------------------------------- layer-1 aggregation + ELU
// R3 per-lane form (redundant exp per 8-lane head group -- cheaper than any
// cross-lane broadcast, R4 post-mortem), 8x unroll, 4 independent acc chains.
__global__ __launch_bounds__(256) void k_agg1(const int* __restrict__ csr,
                                              const int* __restrict__ off,
                                              const unsigned short* __restrict__ h1b,
                                              const float* __restrict__ as1,
                                              const float* __restrict__ ad1,
                                              float* __restrict__ h1e) {
    const int lane = threadIdx.x & 63;
    const int n = (blockIdx.x * blockDim.x + threadIdx.x) >> 6;
    if (n >= N_NODES) return;
    const int beg = off[n], end = off[n + 1];
    const int h0 = lane >> 3;
    const float ad = ad1[n * HEADS + h0];
    float ac0 = 0.f, ac1 = 0.f, ac2 = 0.f, ac3 = 0.f;
    float ds0 = 0.f, ds1 = 0.f, ds2 = 0.f, ds3 = 0.f;
    int i = beg;
    for (; i + 8 <= end; i += 8) {
        int s0 = csr[i],     s1 = csr[i + 1], s2 = csr[i + 2], s3 = csr[i + 3];
        int s4 = csr[i + 4], s5 = csr[i + 5], s6 = csr[i + 6], s7 = csr[i + 7];
        float a0 = as1[s0 * HEADS + h0], a1 = as1[s1 * HEADS + h0];
        float a2 = as1[s2 * HEADS + h0], a3 = as1[s3 * HEADS + h0];
        float a4 = as1[s4 * HEADS + h0], a5 = as1[s5 * HEADS + h0];
        float a6 = as1[s6 * HEADS + h0], a7 = as1[s7 * HEADS + h0];
        float g0 = bf2f(h1b[(size_t)s0 * D1 + lane]), g1 = bf2f(h1b[(size_t)s1 * D1 + lane]);
        float g2 = bf2f(h1b[(size_t)s2 * D1 + lane]), g3 = bf2f(h1b[(size_t)s3 * D1 + lane]);
        float g4 = bf2f(h1b[(size_t)s4 * D1 + lane]), g5 = bf2f(h1b[(size_t)s5 * D1 + lane]);
        float g6 = bf2f(h1b[(size_t)s6 * D1 + lane]), g7 = bf2f(h1b[(size_t)s7 * D1 + lane]);
        float w0 = __expf(leaky(a0 + ad)), w1 = __expf(leaky(a1 + ad));
        float w2 = __expf(leaky(a2 + ad)), w3 = __expf(leaky(a3 + ad));
        float w4 = __expf(leaky(a4 + ad)), w5 = __expf(leaky(a5 + ad));
        float w6 = __expf(leaky(a6 + ad)), w7 = __expf(leaky(a7 + ad));
        ac0 = fmaf(w0, g0, ac0); ds0 += w0;
        ac1 = fmaf(w1, g1, ac1); ds1 += w1;
        ac2 = fmaf(w2, g2, ac2); ds2 += w2;
        ac3 = fmaf(w3, g3, ac3); ds3 += w3;
        ac0 = fmaf(w4, g4, ac0); ds0 += w4;
        ac1 = fmaf(w5, g5, ac1); ds1 += w5;
        ac2 = fmaf(w6, g6, ac2); ds2 += w6;
        ac3 = fmaf(w7, g7, ac3); ds3 += w7;
    }
    for (; i < end; i++) {
        int s = csr[i];
        float w = __expf(leaky(as1[s * HEADS + h0] + ad));
        ac0 = fmaf(w, bf2f(h1b[(size_t)s * D1 + lane]), ac0);
        ds0 += w;
    }
    float acc = (ac0 + ac1) + (ac2 + ac3);
    float dsum = (ds0 + ds1) + (ds2 + ds3);
    float v = acc / (dsum + 1e-16f);
    float o = v > 0.f ? v : (__expf(v) - 1.f);   // ELU
    h1e[(size_t)n * D1 + lane] = o;
}

// ---------------------------------------------------------------- GEMM2 (thread=row)
__global__ __launch_bounds__(256) void k_gemm2(const float* __restrict__ h1e,
                                               const float* __restrict__ W2f,
                                               const float* __restrict__ A2Sf,
                                               const float* __restrict__ A2Df,
                                               unsigned short* __restrict__ h2b,
                                               float* __restrict__ as2,
                                               float* __restrict__ ad2) {
    const int row = blockIdx.x * blockDim.x + threadIdx.x;
    if (row >= N_NODES) return;
    float acc[NC];
#pragma unroll
    for (int c = 0; c < NC; c++) acc[c] = 0.f;
    const float* xr = h1e + (size_t)row * D1;
    for (int k = 0; k < D1; k += 4) {
        float4 hv = *(const float4*)(xr + k);
#pragma unroll
        for (int c = 0; c < NC; c++) {
            acc[c] = fmaf(hv.x, W2f[(k + 0) * NC + c], acc[c]);
            acc[c] = fmaf(hv.y, W2f[(k + 1) * NC + c], acc[c]);
            acc[c] = fmaf(hv.z, W2f[(k + 2) * NC + c], acc[c]);
            acc[c] = fmaf(hv.w, W2f[(k + 3) * NC + c], acc[c]);
        }
    }
    float ts = 0.f, td = 0.f;
#pragma unroll
    for (int c = 0; c < NC; c++) {
        h2b[(size_t)row * H2S + c] = f2b(acc[c]);
        ts = fmaf(acc[c], A2Sf[c], ts);
        td = fmaf(acc[c], A2Df[c], td);
    }
    as2[row] = ts;
    ad2[row] = td;
}

// ---------------------------------------------------------------- layer-2 aggregation + log_softmax
// R3 per-lane form, 8x unroll, 4 independent acc chains.
__global__ __launch_bounds__(256) void k_agg2(const int* __restrict__ csr,
                                              const int* __restrict__ off,
                                              const unsigned short* __restrict__ h2b,
                                              const float* __restrict__ as2,
                                              const float* __restrict__ ad2,
                                              const int* flags, void* out) {
    const int lane = threadIdx.x & 63;
    const int n = (blockIdx.x * blockDim.x + threadIdx.x) >> 6;
    if (n >= N_NODES) return;
    const int beg = off[n], end = off[n + 1];
    const float ad = ad2[n];
    const bool act = lane < NC;
    const int cl = act ? lane : 0;
    float ac0 = 0.f, ac1 = 0.f, ac2 = 0.f, ac3 = 0.f;
    float ds0 = 0.f, ds1 = 0.f, ds2 = 0.f, ds3 = 0.f;
    int i = beg;
    for (; i + 8 <= end; i += 8) {
        int s0 = csr[i],     s1 = csr[i + 1], s2 = csr[i + 2], s3 = csr[i + 3];
        int s4 = csr[i + 4], s5 = csr[i + 5], s6 = csr[i + 6], s7 = csr[i + 7];
        float a0 = as2[s0], a1 = as2[s1], a2 = as2[s2], a3 = as2[s3];
        float a4 = as2[s4], a5 = as2[s5], a6 = as2[s6], a7 = as2[s7];
        float g0 = bf2f(h2b[(size_t)s0 * H2S + cl]), g1 = bf2f(h2b[(size_t)s1 * H2S + cl]);
        float g2 = bf2f(h2b[(size_t)s2 * H2S + cl]), g3 = bf2f(h2b[(size_t)s3 * H2S + cl]);
        float g4 = bf2f(h2b[(size_t)s4 * H2S + cl]), g5 = bf2f(h2b[(size_t)s5 * H2S + cl]);
        float g6 = bf2f(h2b[(size_t)s6 * H2S + cl]), g7 = bf2f(h2b[(size_t)s7 * H2S + cl]);
        float w0 = __expf(leaky(a0 + ad)), w1 = __expf(leaky(a1 + ad));
        float w2 = __expf(leaky(a2 + ad)), w3 = __expf(leaky(a3 + ad));
        float w4 = __expf(leaky(a4 + ad)), w5 = __expf(leaky(a5 + ad));
        float w6 = __expf(leaky(a6 + ad)), w7 = __expf(leaky(a7 + ad));
        ac0 = fmaf(w0, g0, ac0); ds0 += w0;
        ac1 = fmaf(w1, g1, ac1); ds1 += w1;
        ac2 = fmaf(w2, g2, ac2); ds2 += w2;
        ac3 = fmaf(w3, g3, ac3); ds3 += w3;
        ac0 = fmaf(w4, g4, ac0); ds0 += w4;
        ac1 = fmaf(w5, g5, ac1); ds1 += w5;
        ac2 = fmaf(w6, g6, ac2); ds2 += w6;
        ac3 = fmaf(w7, g7, ac3); ds3 += w7;
    }
    for (; i < end; i++) {
        int s = csr[i];
        float w = __expf(leaky(as2[s] + ad));
        ac0 = fmaf(w, bf2f(h2b[(size_t)s * H2S + cl]), ac0);
        ds0 += w;
    }
    float acc = (ac0 + ac1) + (ac2 + ac3);
    float dsum = (ds0 + ds1) + (ds2 + ds3);
    float val = acc / (dsum + 1e-16f);
    // log_softmax over the 41 classes
    float v = act ? val : -INFINITY;
    float m = v;
#pragma unroll
    for (int o = 1; o < 64; o <<= 1) m = fmaxf(m, __shfl_xor(m, o, 64));
    float ex = act ? __expf(val - m) : 0.f;
#pragma unroll
    for (int o = 1; o < 64; o <<= 1) ex += __shfl_xor(ex, o, 64);
    float res = val - m - __logf(ex);
    if (act) {
        if (flags[0])
            ((float*)out)[(size_t)n * NC + lane] = res;
        else
            ((__hip_bfloat16*)out)[(size_t)n * NC + lane] = __float2bfloat16(res);
    }
}

// ---------------------------------------------------------------- host
extern "C" void kernel_launch(void* const* d_in, const int* in_sizes, int n_in,
                              void* d_out, int out_size, void* d_ws, size_t ws_size,
                              hipStream_t stream) {
    char* p = (char*)d_ws;
    auto alloc = [&](size_t bytes) -> void* {
        void* r = (void*)p;
        p += (bytes + 255) & ~(size_t)255;
        return r;
    };
    int* flags  = (int*)alloc(16);
    unsigned short* W1frag = (unsigned short*)alloc(4 * 16 * 64 * 8 * 2);
    float* A1Sf = (float*)alloc(HEADS * HID * 4);
    float* A1Df = (float*)alloc(HEADS * HID * 4);
    float* W2f  = (float*)alloc((size_t)D1 * NC * 4);
    float* A2Sf = (float*)alloc(NC * 4);
    float* A2Df = (float*)alloc(NC * 4);
    unsigned short* h1b = (unsigned short*)alloc((size_t)N_NODES * D1 * 2);
    float* as1  = (float*)alloc((size_t)N_NODES * HEADS * 4);
    float* ad1  = (float*)alloc((size_t)N_NODES * HEADS * 4);
    float* h1e  = (float*)alloc((size_t)N_NODES * D1 * 4);
    unsigned short* h2b = (unsigned short*)alloc((size_t)N_NODES * H2S * 2);
    float* as2  = (float*)alloc((size_t)N_NODES * 4);
    float* ad2  = (float*)alloc((size_t)N_NODES * 4);
    int* off    = (int*)alloc((size_t)(N_NODES + 1) * 4);
    int* csr    = (int*)alloc((size_t)N_EDGES * 4);
    int* bucket_cnt = (int*)alloc((size_t)NB * 4);
    int* cbase      = (int*)alloc((size_t)(NB + 1) * 4);
    // staging aliases h1e (dead until agg1 writes h1e): 16.06 MB <= 25.6 MB
    unsigned int* staging = (unsigned int*)h1e;

    hipMemsetAsync(bucket_cnt, 0, (size_t)NB * 4, stream);

    k_detect_convert<<<1, 256, 0, stream>>>(d_in[0], d_in[1], d_in[2], d_in[3],
                                            d_in[4], d_in[5], d_in[6], d_in[7],
                                            W1frag, A1Sf, A1Df, W2f, A2Sf, A2Df, flags);
    k_bucket_scatter<<<(N_EDGES + SCHUNK - 1) / SCHUNK, 256, 0, stream>>>(d_in[1], flags, bucket_cnt, staging);
    k_cscan<<<1, 256, 0, stream>>>(bucket_cnt, cbase, off);
    k_csr_build<<<NB, 512, 0, stream>>>(staging, bucket_cnt, cbase, off, csr);

    k_gemm1<<<1563, 256, 0, stream>>>(d_in[0], flags, W1frag, A1Sf, A1Df, h1b, as1, ad1);
    k_agg1<<<25000, 256, 0, stream>>>(csr, off, h1b, as1, ad1, h1e);
    k_gemm2<<<391, 256, 0, stream>>>(h1e, W2f, A2Sf, A2Df, h2b, as2, ad2);
    k_agg2<<<25000, 256, 0, stream>>>(csr, off, h2b, as2, ad2, flags, d_out);
}